// Round 15
// baseline (132.156 us; speedup 1.0000x reference)
//
#include <hip/hip_runtime.h>
#include <hip/hip_bf16.h>
#include <math.h>

#define S_LEN 2048
#define C_DIM 512
#define NH 16
#define HD 32
#define PLANE_U (NH * S_LEN * HD)   // 1,048,576 ushorts = 2MB per plane

typedef __attribute__((ext_vector_type(8)))  short bf16x8;
typedef __attribute__((ext_vector_type(8)))  unsigned short u16x8;
typedef __attribute__((ext_vector_type(4)))  float f32x4;
typedef __attribute__((ext_vector_type(16))) float f32x16;
typedef __attribute__((ext_vector_type(4)))  unsigned int u32x4;

#if __has_builtin(__builtin_amdgcn_exp2f)
#define EXP2(x) __builtin_amdgcn_exp2f(x)
#else
#define EXP2(x) exp2f(x)
#endif

// pack 2 floats -> 2 bf16 in one dword via v_cvt_pk_bf16_f32 (RNE); a = low
__device__ __forceinline__ unsigned int pk_bf16(float a, float b) {
    float2 f; f.x = a; f.y = b;
    __hip_bfloat162 t = __float22bfloat162_rn(f);
    return *reinterpret_cast<unsigned int*>(&t);
}

// ---------------- projection: complex GEMM via bf16 MFMA ------------------
// (unchanged from round 14 — passed, absmax 0.039)
#define PROW 40   // padded LDS row stride in ushorts (80B, 16B-aligned)

__global__ __launch_bounds__(256)
void proj_mfma(const float* __restrict__ Q, const float* __restrict__ V,
               const float* __restrict__ K,
               const float* __restrict__ Wq, const float* __restrict__ bq,
               const float* __restrict__ Wk, const float* __restrict__ bk,
               const float* __restrict__ Wv, const float* __restrict__ bv,
               unsigned short* __restrict__ ws)
{
    const int z = blockIdx.z;
    const float *X, *W, *b;
    if (z == 0)      { X = Q; W = Wq; b = bq; }
    else if (z == 1) { X = K; W = Wk; b = bk; }
    else             { X = V; W = Wv; b = bv; }
    const bool full = (z < 2);

    const int s0 = blockIdx.x * 64;
    const int o0 = blockIdx.y * 64;

    const float2 *Asrc, *Bsrc; int arow0, brow0;
    if (full) { Asrc = (const float2*)W; arow0 = o0; Bsrc = (const float2*)X; brow0 = s0; }
    else      { Asrc = (const float2*)X; arow0 = s0; Bsrc = (const float2*)W; brow0 = o0; }

    __shared__ __align__(16) unsigned short LBrh[64*PROW], LBrl[64*PROW];
    __shared__ __align__(16) unsigned short LBih[64*PROW], LBil[64*PROW];

    const int t    = threadIdx.x;
    const int wave = t >> 6;
    const int lr   = t & 15;
    const int g    = (t & 63) >> 4;
    const int srow = t >> 2;        // B staging row 0..63
    const int sk8  = (t & 3) * 8;   // B staging k chunk (8 complex)

    const f32x4 zf = {0.f,0.f,0.f,0.f};
    f32x4 accR[4], accI[4];
    #pragma unroll
    for (int i = 0; i < 4; ++i) { accR[i] = zf; accI[i] = zf; }

    // per-lane A row (wave-private) — direct global loads each k-step
    const float4* Arow4 = (const float4*)(Asrc + (size_t)(arow0 + wave*16 + lr)*C_DIM);

    for (int k0 = 0; k0 < C_DIM; k0 += 32) {
        // issue A-fragment global load early (overlaps barrier + B staging)
        const float4* a4 = Arow4 + ((k0 + g*8) >> 1);   // 8 complex = 4 float4
        float4 A0 = a4[0], A1 = a4[1], A2 = a4[2], A3 = a4[3];

        __syncthreads();   // previous B tile fully consumed
        // ---- stage B tile (shared across waves) ----
        {
            const float4* s4 = (const float4*)(Bsrc + (size_t)(brow0 + srow)*C_DIM + k0 + sk8);
            float4 f0 = s4[0], f1 = s4[1], f2v = s4[2], f3 = s4[3];
            float re[8] = {f0.x,f0.z,f1.x,f1.z,f2v.x,f2v.z,f3.x,f3.z};
            float im[8] = {f0.y,f0.w,f1.y,f1.w,f2v.y,f2v.w,f3.y,f3.w};
            u32x4 rh, ih, rl, il;
            if (full) {
                #pragma unroll
                for (int p2 = 0; p2 < 4; ++p2) {
                    float r0f = re[2*p2], r1f = re[2*p2+1];
                    float i0f = im[2*p2], i1f = im[2*p2+1];
                    unsigned int br0 = __float_as_uint(r0f), br1 = __float_as_uint(r1f);
                    unsigned int bi0 = __float_as_uint(i0f), bi1 = __float_as_uint(i1f);
                    rh[p2] = __builtin_amdgcn_perm(br1, br0, 0x07060302u);  // [hi16(r1):hi16(r0)]
                    ih[p2] = __builtin_amdgcn_perm(bi1, bi0, 0x07060302u);
                    rl[p2] = pk_bf16(r0f - __uint_as_float(br0 & 0xFFFF0000u),
                                     r1f - __uint_as_float(br1 & 0xFFFF0000u));
                    il[p2] = pk_bf16(i0f - __uint_as_float(bi0 & 0xFFFF0000u),
                                     i1f - __uint_as_float(bi1 & 0xFFFF0000u));
                }
            } else {
                #pragma unroll
                for (int p2 = 0; p2 < 4; ++p2) {
                    rh[p2] = pk_bf16(re[2*p2], re[2*p2+1]);
                    ih[p2] = pk_bf16(im[2*p2], im[2*p2+1]);
                }
            }
            int wb = srow*PROW + sk8;
            *(u32x4*)&LBrh[wb] = rh; *(u32x4*)&LBih[wb] = ih;
            if (full) { *(u32x4*)&LBrl[wb] = rl; *(u32x4*)&LBil[wb] = il; }
        }

        // ---- convert A fragment in-register (while B stores land) ----
        bf16x8 aRH, aIH, aRL, aIL;
        {
            float re[8] = {A0.x,A0.z,A1.x,A1.z,A2.x,A2.z,A3.x,A3.z};
            float im[8] = {A0.y,A0.w,A1.y,A1.w,A2.y,A2.w,A3.y,A3.w};
            u32x4 rh, ih, rl, il;
            if (full) {
                #pragma unroll
                for (int p2 = 0; p2 < 4; ++p2) {
                    float r0f = re[2*p2], r1f = re[2*p2+1];
                    float i0f = im[2*p2], i1f = im[2*p2+1];
                    unsigned int br0 = __float_as_uint(r0f), br1 = __float_as_uint(r1f);
                    unsigned int bi0 = __float_as_uint(i0f), bi1 = __float_as_uint(i1f);
                    rh[p2] = __builtin_amdgcn_perm(br1, br0, 0x07060302u);
                    ih[p2] = __builtin_amdgcn_perm(bi1, bi0, 0x07060302u);
                    rl[p2] = pk_bf16(r0f - __uint_as_float(br0 & 0xFFFF0000u),
                                     r1f - __uint_as_float(br1 & 0xFFFF0000u));
                    il[p2] = pk_bf16(i0f - __uint_as_float(bi0 & 0xFFFF0000u),
                                     i1f - __uint_as_float(bi1 & 0xFFFF0000u));
                }
                aRL = *(bf16x8*)&rl; aIL = *(bf16x8*)&il;
            } else {
                #pragma unroll
                for (int p2 = 0; p2 < 4; ++p2) {
                    rh[p2] = pk_bf16(re[2*p2], re[2*p2+1]);
                    ih[p2] = pk_bf16(im[2*p2], im[2*p2+1]);
                }
            }
            aRH = *(bf16x8*)&rh; aIH = *(bf16x8*)&ih;
        }
        bf16x8 aIHn;
        #pragma unroll
        for (int j = 0; j < 8; ++j) aIHn[j] = aIH[j] ^ (short)0x8000;

        __syncthreads();   // B tile visible

        if (full) {
            bf16x8 aILn;
            #pragma unroll
            for (int j = 0; j < 8; ++j) aILn[j] = aIL[j] ^ (short)0x8000;

            #pragma unroll
            for (int tile = 0; tile < 4; ++tile) {
                const int bb = (tile*16 + lr)*PROW + g*8;
                bf16x8 bRH = *(const bf16x8*)&LBrh[bb];
                bf16x8 bRL = *(const bf16x8*)&LBrl[bb];
                bf16x8 bIH = *(const bf16x8*)&LBih[bb];
                bf16x8 bIL = *(const bf16x8*)&LBil[bb];
                accR[tile] = __builtin_amdgcn_mfma_f32_16x16x32_bf16(aRH,  bRH, accR[tile], 0,0,0);
                accR[tile] = __builtin_amdgcn_mfma_f32_16x16x32_bf16(aRL,  bRH, accR[tile], 0,0,0);
                accR[tile] = __builtin_amdgcn_mfma_f32_16x16x32_bf16(aRH,  bRL, accR[tile], 0,0,0);
                accR[tile] = __builtin_amdgcn_mfma_f32_16x16x32_bf16(aIHn, bIH, accR[tile], 0,0,0);
                accR[tile] = __builtin_amdgcn_mfma_f32_16x16x32_bf16(aILn, bIH, accR[tile], 0,0,0);
                accR[tile] = __builtin_amdgcn_mfma_f32_16x16x32_bf16(aIHn, bIL, accR[tile], 0,0,0);
                accI[tile] = __builtin_amdgcn_mfma_f32_16x16x32_bf16(aRH,  bIH, accI[tile], 0,0,0);
                accI[tile] = __builtin_amdgcn_mfma_f32_16x16x32_bf16(aRL,  bIH, accI[tile], 0,0,0);
                accI[tile] = __builtin_amdgcn_mfma_f32_16x16x32_bf16(aRH,  bIL, accI[tile], 0,0,0);
                accI[tile] = __builtin_amdgcn_mfma_f32_16x16x32_bf16(aIH,  bRH, accI[tile], 0,0,0);
                accI[tile] = __builtin_amdgcn_mfma_f32_16x16x32_bf16(aIL,  bRH, accI[tile], 0,0,0);
                accI[tile] = __builtin_amdgcn_mfma_f32_16x16x32_bf16(aIH,  bRL, accI[tile], 0,0,0);
            }
        } else {
            #pragma unroll
            for (int tile = 0; tile < 4; ++tile) {
                const int bb = (tile*16 + lr)*PROW + g*8;
                bf16x8 bRH = *(const bf16x8*)&LBrh[bb];
                bf16x8 bIH = *(const bf16x8*)&LBih[bb];
                accR[tile] = __builtin_amdgcn_mfma_f32_16x16x32_bf16(aRH,  bRH, accR[tile], 0,0,0);
                accR[tile] = __builtin_amdgcn_mfma_f32_16x16x32_bf16(aIHn, bIH, accR[tile], 0,0,0);
                accI[tile] = __builtin_amdgcn_mfma_f32_16x16x32_bf16(aRH,  bIH, accI[tile], 0,0,0);
                accI[tile] = __builtin_amdgcn_mfma_f32_16x16x32_bf16(aIH,  bRH, accI[tile], 0,0,0);
            }
        }
    }

    // ---- epilogue ----
    const float2* b2 = (const float2*)b;
    if (full) {
        // Q plane pre-scaled by log2(e)/sqrt(32): softmax uses exp2 directly
        const float osc = (z == 0) ? 0.2550348677f : 1.0f;
        unsigned short* pr = ws + (z == 0 ? 0 : 2) * (size_t)PLANE_U;
        unsigned short* pi = pr + PLANE_U;
        const int obase = o0 + wave*16 + g*4;
        const int h = obase >> 5, d0 = obase & 31;
        float bR[4], bI[4];
        #pragma unroll
        for (int r = 0; r < 4; ++r) { float2 bb = b2[obase + r]; bR[r] = bb.x; bI[r] = bb.y; }
        #pragma unroll
        for (int tile = 0; tile < 4; ++tile) {
            int s = s0 + tile*16 + lr;
            size_t idx = ((size_t)h*S_LEN + s)*HD + d0;
            uint2 pkR, pkI;
            pkR.x = pk_bf16((accR[tile][0]+bR[0])*osc, (accR[tile][1]+bR[1])*osc);
            pkR.y = pk_bf16((accR[tile][2]+bR[2])*osc, (accR[tile][3]+bR[3])*osc);
            pkI.x = pk_bf16((accI[tile][0]+bI[0])*osc, (accI[tile][1]+bI[1])*osc);
            pkI.y = pk_bf16((accI[tile][2]+bI[2])*osc, (accI[tile][3]+bI[3])*osc);
            *(uint2*)&pr[idx] = pkR;
            *(uint2*)&pi[idx] = pkI;
        }
    } else {
        // chunk-interleaved V^T: VT[h][c][d][{re,im}][32], c = s>>5
        unsigned short* vt = ws + 4 * (size_t)PLANE_U;
        const int sbase = s0 + wave*16 + g*4;
        const int c  = sbase >> 5;
        const int j0 = sbase & 31;
        #pragma unroll
        for (int tile = 0; tile < 4; ++tile) {
            int o = o0 + tile*16 + lr;
            int h = o >> 5, d = o & 31;
            float2 bb = b2[o];
            size_t base = ((((size_t)h*64 + c)*32 + d) << 6) + j0;
            uint2 pkR, pkI;
            pkR.x = pk_bf16(accR[tile][0]+bb.x, accR[tile][1]+bb.x);
            pkR.y = pk_bf16(accR[tile][2]+bb.x, accR[tile][3]+bb.x);
            pkI.x = pk_bf16(accI[tile][0]+bb.y, accI[tile][1]+bb.y);
            pkI.y = pk_bf16(accI[tile][2]+bb.y, accI[tile][3]+bb.y);
            *(uint2*)&vt[base]      = pkR;
            *(uint2*)&vt[base + 32] = pkI;
        }
    }
}

// ---------------- MFMA flash attention: 32x32x16, split-K 4, K-pipelined --
// As round 14 (kappa-permuted QK^T -> P direct to PV B-frag; VT chunk-
// interleaved one-line loads; exp2 softmax) PLUS an explicit software
// pipeline on the K fragments: the loop is fully unrolled and group n+1's
// four K loads are ISSUED before group n's QK chain (ping-pong register
// buffers, compile-time indices). K L2-latency (~200cy), previously exposed
// at the head of every group, now hides under the previous group's compute.
// V loads keep their natural slack (consumed after QK+softmax). s_setprio
// wraps the MFMA clusters (waves sit in different phases -> arbitration).
#define RROW 33

__global__ __launch_bounds__(256, 4)
void attn_mfma(const unsigned short* __restrict__ ws, float* __restrict__ out)
{
    const int bid   = blockIdx.x;       // 64 q-blocks x 16 heads
    const int h     = bid & (NH - 1);   // bid%8 = head%8 -> per-XCD KV locality
    const int qblk  = bid >> 4;         // 0..63
    const int wave  = threadIdx.x >> 6; // 0..3 -> k-range owner
    const int l     = threadIdx.x & 63;
    const int q     = l & 31;           // q-col AND VT d-row AND PV q-col
    const int b     = l >> 5;           // lane half

    const unsigned short* qr = ws + 0*(size_t)PLANE_U + (size_t)h*S_LEN*HD;
    const unsigned short* qi = ws + 1*(size_t)PLANE_U + (size_t)h*S_LEN*HD;
    const unsigned short* kr = ws + 2*(size_t)PLANE_U + (size_t)h*S_LEN*HD;
    const unsigned short* ki = ws + 3*(size_t)PLANE_U + (size_t)h*S_LEN*HD;
    const unsigned short* vt = ws + 4*(size_t)PLANE_U + ((size_t)h << 17); // 64*32*64

    const int q0 = qblk * 32;

    // key -> A-row permutation; fixed per lane
    const int row   = q;
    const int kappa = (row & 16) + (((row >> 2) & 1) << 3) + (row & 3)
                    + (((row >> 3) & 1) << 2);

    // Q fragments (B-operand): lane supplies Q[q][d = b*8+j] (lo) / +16 (hi)
    bf16x8 bQr_lo = *(const bf16x8*)&qr[(size_t)(q0 + q)*HD + b*8];
    bf16x8 bQr_hi = *(const bf16x8*)&qr[(size_t)(q0 + q)*HD + 16 + b*8];
    bf16x8 bQi_lo = *(const bf16x8*)&qi[(size_t)(q0 + q)*HD + b*8];
    bf16x8 bQi_hi = *(const bf16x8*)&qi[(size_t)(q0 + q)*HD + 16 + b*8];

    // LDS only for the end-of-kernel two-stage combine: [2][32][33] float2
    __shared__ __align__(16) float2 red[2*32*RROW];

    f32x16 accR, accI;
    #pragma unroll
    for (int r = 0; r < 16; ++r) { accR[r] = 0.f; accI[r] = 0.f; }
    float lsum = 0.f;

    const f32x16 z16 = {0,0,0,0,0,0,0,0,0,0,0,0,0,0,0,0};
    const int kbeg = wave * 512;
    const size_t krow0 = (size_t)(kbeg + kappa)*HD + b*8;

    // ping-pong K fragment buffers (compile-time indexed via full unroll)
    bf16x8 pKr_lo[2], pKr_hi[2], pKi_lo[2], pKi_hi[2];
    pKr_lo[0] = *(const bf16x8*)&kr[krow0];
    pKr_hi[0] = *(const bf16x8*)&kr[krow0 + 16];
    pKi_lo[0] = *(const bf16x8*)&ki[krow0];
    pKi_hi[0] = *(const bf16x8*)&ki[krow0 + 16];

    #pragma unroll
    for (int n = 0; n < 16; ++n) {
        const int cur = n & 1, nxt = cur ^ 1;
        const int k0  = kbeg + n*32;

        // ---- V fragments for THIS group (one 128B line per d-row; slack =
        //      the whole QK chain + softmax) ----
        const size_t vbase = (((size_t)(k0 >> 5)*32 + q) << 6) + b*8;
        bf16x8 aVr_lo = *(const bf16x8*)&vt[vbase];
        bf16x8 aVr_hi = *(const bf16x8*)&vt[vbase + 16];
        bf16x8 aVi_lo = *(const bf16x8*)&vt[vbase + 32];
        bf16x8 aVi_hi = *(const bf16x8*)&vt[vbase + 48];

        // ---- PREFETCH next group's K fragments (latency hides under this
        //      group's QK chain + softmax + PV) ----
        if (n < 15) {
            const size_t krow = (size_t)(k0 + 32 + kappa)*HD + b*8;
            pKr_lo[nxt] = *(const bf16x8*)&kr[krow];
            pKr_hi[nxt] = *(const bf16x8*)&kr[krow + 16];
            pKi_lo[nxt] = *(const bf16x8*)&ki[krow];
            pKi_hi[nxt] = *(const bf16x8*)&ki[krow + 16];
        }

        // ---- -Ki transient ----
        bf16x8 aKin_lo, aKin_hi;
        #pragma unroll
        for (int j = 0; j < 4; ++j) {
            ((unsigned int*)&aKin_lo)[j] = ((const unsigned int*)&pKi_lo[cur])[j] ^ 0x80008000u;
            ((unsigned int*)&aKin_hi)[j] = ((const unsigned int*)&pKi_hi[cur])[j] ^ 0x80008000u;
        }
        // ---- QK^T: 8 mfma, two independent 4-chains ----
        __builtin_amdgcn_s_setprio(1);
        f32x16 sR = __builtin_amdgcn_mfma_f32_32x32x16_bf16(pKr_lo[cur], bQr_lo, z16, 0, 0, 0);
        f32x16 sI = __builtin_amdgcn_mfma_f32_32x32x16_bf16(aKin_lo,     bQr_lo, z16, 0, 0, 0);
        sR = __builtin_amdgcn_mfma_f32_32x32x16_bf16(pKr_hi[cur], bQr_hi, sR, 0, 0, 0);
        sI = __builtin_amdgcn_mfma_f32_32x32x16_bf16(aKin_hi,     bQr_hi, sI, 0, 0, 0);
        sR = __builtin_amdgcn_mfma_f32_32x32x16_bf16(pKi_lo[cur], bQi_lo, sR, 0, 0, 0);
        sI = __builtin_amdgcn_mfma_f32_32x32x16_bf16(pKr_lo[cur], bQi_lo, sI, 0, 0, 0);
        sR = __builtin_amdgcn_mfma_f32_32x32x16_bf16(pKi_hi[cur], bQi_hi, sR, 0, 0, 0);
        sI = __builtin_amdgcn_mfma_f32_32x32x16_bf16(pKr_hi[cur], bQi_hi, sI, 0, 0, 0);
        __builtin_amdgcn_s_setprio(0);
        // ---- softmax: p[r] lands exactly in PV B-frag order ----
        bf16x8 bP1, bP2;
        unsigned int* p1 = (unsigned int*)&bP1;
        unsigned int* p2 = (unsigned int*)&bP2;
        #pragma unroll
        for (int r2 = 0; r2 < 8; ++r2) {
            int r = 2*r2;
            float v0 = EXP2(__builtin_amdgcn_sqrtf(fmaf(sR[r],   sR[r],   sI[r]*sI[r])));
            float v1 = EXP2(__builtin_amdgcn_sqrtf(fmaf(sR[r+1], sR[r+1], sI[r+1]*sI[r+1])));
            lsum += v0 + v1;
            if (r2 < 4) p1[r2]     = pk_bf16(v0, v1);
            else        p2[r2 - 4] = pk_bf16(v0, v1);
        }
        // ---- PV: A = VT (one line), B = P in-register ----
        __builtin_amdgcn_s_setprio(1);
        accR = __builtin_amdgcn_mfma_f32_32x32x16_bf16(aVr_lo, bP1, accR, 0, 0, 0);
        accI = __builtin_amdgcn_mfma_f32_32x32x16_bf16(aVi_lo, bP1, accI, 0, 0, 0);
        accR = __builtin_amdgcn_mfma_f32_32x32x16_bf16(aVr_hi, bP2, accR, 0, 0, 0);
        accI = __builtin_amdgcn_mfma_f32_32x32x16_bf16(aVi_hi, bP2, accI, 0, 0, 0);
        __builtin_amdgcn_s_setprio(0);
    }

    // lane pair (l, l^32) handled complementary key halves of the same q
    lsum += __shfl_xor(lsum, 32);

    // ---- two-stage combine: waves 0,1 write; 2,3 add; all reduce ----
    const int rrow = ((wave & 1) * 32 + q) * RROW;
    __syncthreads();
    if (wave < 2) {
        #pragma unroll
        for (int r = 0; r < 16; ++r) {
            int d = (r & 3) + 8*(r >> 2) + 4*b;   // PV D row = output d
            red[rrow + d] = make_float2(accR[r], accI[r]);
        }
        if (b == 0) red[rrow + 32].x = lsum;
    }
    __syncthreads();
    if (wave >= 2) {
        #pragma unroll
        for (int r = 0; r < 16; ++r) {
            int d = (r & 3) + 8*(r >> 2) + 4*b;
            float2 v = red[rrow + d];
            v.x += accR[r]; v.y += accI[r];
            red[rrow + d] = v;
        }
        if (b == 0) red[rrow + 32].x += lsum;
    }
    __syncthreads();

    // thread i: q-row = i>>3, d = (i&7)*4 .. +3 ; sum 2 stage-partials
    {
        const int i  = threadIdx.x;
        const int oq = i >> 3;
        const int d0 = (i & 7) * 4;
        float sl = red[oq*RROW + 32].x + red[(32 + oq)*RROW + 32].x;
        float inv = 1.0f / sl;
        float2* o2 = (float2*)out;
        #pragma unroll
        for (int dd = 0; dd < 4; ++dd) {
            int d = d0 + dd;
            float2 v0 = red[oq*RROW + d];
            float2 v1 = red[(32 + oq)*RROW + d];
            o2[(size_t)(q0 + oq)*C_DIM + h*HD + d] =
                make_float2((v0.x + v1.x)*inv, (v0.y + v1.y)*inv);
        }
    }
}

extern "C" void kernel_launch(void* const* d_in, const int* in_sizes, int n_in,
                              void* d_out, int out_size, void* d_ws, size_t ws_size,
                              hipStream_t stream)
{
    const float* Q  = (const float*)d_in[0];
    const float* V  = (const float*)d_in[1];
    const float* K  = (const float*)d_in[2];
    const float* Wq = (const float*)d_in[3];
    const float* bq = (const float*)d_in[4];
    const float* Wk = (const float*)d_in[5];
    const float* bk = (const float*)d_in[6];
    const float* Wv = (const float*)d_in[7];
    const float* bv = (const float*)d_in[8];
    unsigned short* ws = (unsigned short*)d_ws;   // 4 qk planes + 2MB*2 VT = 12MB
    float* out = (float*)d_out;

    dim3 gp(S_LEN/64, C_DIM/64, 3);
    proj_mfma<<<gp, 256, 0, stream>>>(Q, V, K, Wq, bq, Wk, bk, Wv, bv, ws);

    attn_mfma<<<dim3(64*NH), 256, 0, stream>>>(ws, out);
}

// Round 16
// 81.715 us; speedup vs baseline: 1.6173x; 1.6173x over previous
//
#include <hip/hip_runtime.h>
#include <hip/hip_bf16.h>
#include <math.h>

#define S_LEN 2048
#define C_DIM 512
#define NH 16
#define HD 32
#define PLANE_U (NH * S_LEN * HD)   // 1,048,576 ushorts = 2MB per plane

typedef __attribute__((ext_vector_type(8)))  short bf16x8;
typedef __attribute__((ext_vector_type(8)))  unsigned short u16x8;
typedef __attribute__((ext_vector_type(4)))  float f32x4;
typedef __attribute__((ext_vector_type(16))) float f32x16;
typedef __attribute__((ext_vector_type(4)))  unsigned int u32x4;

#if __has_builtin(__builtin_amdgcn_exp2f)
#define EXP2(x) __builtin_amdgcn_exp2f(x)
#else
#define EXP2(x) exp2f(x)
#endif

// pack 2 floats -> 2 bf16 in one dword via v_cvt_pk_bf16_f32 (RNE); a = low
__device__ __forceinline__ unsigned int pk_bf16(float a, float b) {
    float2 f; f.x = a; f.y = b;
    __hip_bfloat162 t = __float22bfloat162_rn(f);
    return *reinterpret_cast<unsigned int*>(&t);
}

// ---------------- projection: complex GEMM via bf16 MFMA ------------------
// A-operand (16 wave-private rows) loaded directly from global, converted
// in-register; only the shared B tile staged in LDS.
// z==0 (q): D = W·X^T -> natural [h][s][d], PRE-SCALED by log2(e)/sqrt(32).
// z==1 (k): D = W·X^T -> FRAGMENT-ORDER plane KF[h][c][frag][lane][8]:
//           frag = plane*2+(d>=16); lane = ((d&15)>>3)*32 + kappa(key&31)
//           (kappa = swap bits 2<->3, self-inverse). attn's 4 K loads are
//           then CONTIGUOUS 1KB each — no scatter, no per-lane addressing.
// z==2 (v): D = X·W^T -> FRAGMENT-ORDER plane VF[h][c][frag][lane][8]:
//           frag = plane*2+(j>=16); lane = ((j&15)>>3)*32 + d.
#define PROW 40   // padded LDS row stride in ushorts (80B, 16B-aligned)

__global__ __launch_bounds__(256)
void proj_mfma(const float* __restrict__ Q, const float* __restrict__ V,
               const float* __restrict__ K,
               const float* __restrict__ Wq, const float* __restrict__ bq,
               const float* __restrict__ Wk, const float* __restrict__ bk,
               const float* __restrict__ Wv, const float* __restrict__ bv,
               unsigned short* __restrict__ ws)
{
    const int z = blockIdx.z;
    const float *X, *W, *b;
    if (z == 0)      { X = Q; W = Wq; b = bq; }
    else if (z == 1) { X = K; W = Wk; b = bk; }
    else             { X = V; W = Wv; b = bv; }
    const bool full = (z < 2);

    const int s0 = blockIdx.x * 64;
    const int o0 = blockIdx.y * 64;

    const float2 *Asrc, *Bsrc; int arow0, brow0;
    if (full) { Asrc = (const float2*)W; arow0 = o0; Bsrc = (const float2*)X; brow0 = s0; }
    else      { Asrc = (const float2*)X; arow0 = s0; Bsrc = (const float2*)W; brow0 = o0; }

    __shared__ __align__(16) unsigned short LBrh[64*PROW], LBrl[64*PROW];
    __shared__ __align__(16) unsigned short LBih[64*PROW], LBil[64*PROW];

    const int t    = threadIdx.x;
    const int wave = t >> 6;
    const int lr   = t & 15;
    const int g    = (t & 63) >> 4;
    const int srow = t >> 2;        // B staging row 0..63
    const int sk8  = (t & 3) * 8;   // B staging k chunk (8 complex)

    const f32x4 zf = {0.f,0.f,0.f,0.f};
    f32x4 accR[4], accI[4];
    #pragma unroll
    for (int i = 0; i < 4; ++i) { accR[i] = zf; accI[i] = zf; }

    // per-lane A row (wave-private) — direct global loads each k-step
    const float4* Arow4 = (const float4*)(Asrc + (size_t)(arow0 + wave*16 + lr)*C_DIM);

    for (int k0 = 0; k0 < C_DIM; k0 += 32) {
        // issue A-fragment global load early (overlaps barrier + B staging)
        const float4* a4 = Arow4 + ((k0 + g*8) >> 1);   // 8 complex = 4 float4
        float4 A0 = a4[0], A1 = a4[1], A2 = a4[2], A3 = a4[3];

        __syncthreads();   // previous B tile fully consumed
        // ---- stage B tile (shared across waves) ----
        {
            const float4* s4 = (const float4*)(Bsrc + (size_t)(brow0 + srow)*C_DIM + k0 + sk8);
            float4 f0 = s4[0], f1 = s4[1], f2v = s4[2], f3 = s4[3];
            float re[8] = {f0.x,f0.z,f1.x,f1.z,f2v.x,f2v.z,f3.x,f3.z};
            float im[8] = {f0.y,f0.w,f1.y,f1.w,f2v.y,f2v.w,f3.y,f3.w};
            u32x4 rh, ih, rl, il;
            if (full) {
                #pragma unroll
                for (int p2 = 0; p2 < 4; ++p2) {
                    float r0f = re[2*p2], r1f = re[2*p2+1];
                    float i0f = im[2*p2], i1f = im[2*p2+1];
                    unsigned int br0 = __float_as_uint(r0f), br1 = __float_as_uint(r1f);
                    unsigned int bi0 = __float_as_uint(i0f), bi1 = __float_as_uint(i1f);
                    rh[p2] = __builtin_amdgcn_perm(br1, br0, 0x07060302u);  // [hi16(r1):hi16(r0)]
                    ih[p2] = __builtin_amdgcn_perm(bi1, bi0, 0x07060302u);
                    rl[p2] = pk_bf16(r0f - __uint_as_float(br0 & 0xFFFF0000u),
                                     r1f - __uint_as_float(br1 & 0xFFFF0000u));
                    il[p2] = pk_bf16(i0f - __uint_as_float(bi0 & 0xFFFF0000u),
                                     i1f - __uint_as_float(bi1 & 0xFFFF0000u));
                }
            } else {
                #pragma unroll
                for (int p2 = 0; p2 < 4; ++p2) {
                    rh[p2] = pk_bf16(re[2*p2], re[2*p2+1]);
                    ih[p2] = pk_bf16(im[2*p2], im[2*p2+1]);
                }
            }
            int wb = srow*PROW + sk8;
            *(u32x4*)&LBrh[wb] = rh; *(u32x4*)&LBih[wb] = ih;
            if (full) { *(u32x4*)&LBrl[wb] = rl; *(u32x4*)&LBil[wb] = il; }
        }

        // ---- convert A fragment in-register (while B stores land) ----
        bf16x8 aRH, aIH, aRL, aIL;
        {
            float re[8] = {A0.x,A0.z,A1.x,A1.z,A2.x,A2.z,A3.x,A3.z};
            float im[8] = {A0.y,A0.w,A1.y,A1.w,A2.y,A2.w,A3.y,A3.w};
            u32x4 rh, ih, rl, il;
            if (full) {
                #pragma unroll
                for (int p2 = 0; p2 < 4; ++p2) {
                    float r0f = re[2*p2], r1f = re[2*p2+1];
                    float i0f = im[2*p2], i1f = im[2*p2+1];
                    unsigned int br0 = __float_as_uint(r0f), br1 = __float_as_uint(r1f);
                    unsigned int bi0 = __float_as_uint(i0f), bi1 = __float_as_uint(i1f);
                    rh[p2] = __builtin_amdgcn_perm(br1, br0, 0x07060302u);
                    ih[p2] = __builtin_amdgcn_perm(bi1, bi0, 0x07060302u);
                    rl[p2] = pk_bf16(r0f - __uint_as_float(br0 & 0xFFFF0000u),
                                     r1f - __uint_as_float(br1 & 0xFFFF0000u));
                    il[p2] = pk_bf16(i0f - __uint_as_float(bi0 & 0xFFFF0000u),
                                     i1f - __uint_as_float(bi1 & 0xFFFF0000u));
                }
                aRL = *(bf16x8*)&rl; aIL = *(bf16x8*)&il;
            } else {
                #pragma unroll
                for (int p2 = 0; p2 < 4; ++p2) {
                    rh[p2] = pk_bf16(re[2*p2], re[2*p2+1]);
                    ih[p2] = pk_bf16(im[2*p2], im[2*p2+1]);
                }
            }
            aRH = *(bf16x8*)&rh; aIH = *(bf16x8*)&ih;
        }
        bf16x8 aIHn;
        #pragma unroll
        for (int j = 0; j < 8; ++j) aIHn[j] = aIH[j] ^ (short)0x8000;

        __syncthreads();   // B tile visible

        if (full) {
            bf16x8 aILn;
            #pragma unroll
            for (int j = 0; j < 8; ++j) aILn[j] = aIL[j] ^ (short)0x8000;

            #pragma unroll
            for (int tile = 0; tile < 4; ++tile) {
                const int bb = (tile*16 + lr)*PROW + g*8;
                bf16x8 bRH = *(const bf16x8*)&LBrh[bb];
                bf16x8 bRL = *(const bf16x8*)&LBrl[bb];
                bf16x8 bIH = *(const bf16x8*)&LBih[bb];
                bf16x8 bIL = *(const bf16x8*)&LBil[bb];
                accR[tile] = __builtin_amdgcn_mfma_f32_16x16x32_bf16(aRH,  bRH, accR[tile], 0,0,0);
                accR[tile] = __builtin_amdgcn_mfma_f32_16x16x32_bf16(aRL,  bRH, accR[tile], 0,0,0);
                accR[tile] = __builtin_amdgcn_mfma_f32_16x16x32_bf16(aRH,  bRL, accR[tile], 0,0,0);
                accR[tile] = __builtin_amdgcn_mfma_f32_16x16x32_bf16(aIHn, bIH, accR[tile], 0,0,0);
                accR[tile] = __builtin_amdgcn_mfma_f32_16x16x32_bf16(aILn, bIH, accR[tile], 0,0,0);
                accR[tile] = __builtin_amdgcn_mfma_f32_16x16x32_bf16(aIHn, bIL, accR[tile], 0,0,0);
                accI[tile] = __builtin_amdgcn_mfma_f32_16x16x32_bf16(aRH,  bIH, accI[tile], 0,0,0);
                accI[tile] = __builtin_amdgcn_mfma_f32_16x16x32_bf16(aRL,  bIH, accI[tile], 0,0,0);
                accI[tile] = __builtin_amdgcn_mfma_f32_16x16x32_bf16(aRH,  bIL, accI[tile], 0,0,0);
                accI[tile] = __builtin_amdgcn_mfma_f32_16x16x32_bf16(aIH,  bRH, accI[tile], 0,0,0);
                accI[tile] = __builtin_amdgcn_mfma_f32_16x16x32_bf16(aIL,  bRH, accI[tile], 0,0,0);
                accI[tile] = __builtin_amdgcn_mfma_f32_16x16x32_bf16(aIH,  bRL, accI[tile], 0,0,0);
            }
        } else {
            #pragma unroll
            for (int tile = 0; tile < 4; ++tile) {
                const int bb = (tile*16 + lr)*PROW + g*8;
                bf16x8 bRH = *(const bf16x8*)&LBrh[bb];
                bf16x8 bIH = *(const bf16x8*)&LBih[bb];
                accR[tile] = __builtin_amdgcn_mfma_f32_16x16x32_bf16(aRH,  bRH, accR[tile], 0,0,0);
                accR[tile] = __builtin_amdgcn_mfma_f32_16x16x32_bf16(aIHn, bIH, accR[tile], 0,0,0);
                accI[tile] = __builtin_amdgcn_mfma_f32_16x16x32_bf16(aRH,  bIH, accI[tile], 0,0,0);
                accI[tile] = __builtin_amdgcn_mfma_f32_16x16x32_bf16(aIH,  bRH, accI[tile], 0,0,0);
            }
        }
    }

    // ---- epilogue ----
    const float2* b2 = (const float2*)b;
    if (z == 0) {
        // Q plane natural [h][s][d], pre-scaled by log2(e)/sqrt(32)
        const float osc = 0.2550348677f;
        unsigned short* pr = ws;
        unsigned short* pi = pr + PLANE_U;
        const int obase = o0 + wave*16 + g*4;
        const int hh = obase >> 5, d0 = obase & 31;
        float bR[4], bI[4];
        #pragma unroll
        for (int r = 0; r < 4; ++r) { float2 bb = b2[obase + r]; bR[r] = bb.x; bI[r] = bb.y; }
        #pragma unroll
        for (int tile = 0; tile < 4; ++tile) {
            int s = s0 + tile*16 + lr;
            size_t idx = ((size_t)hh*S_LEN + s)*HD + d0;
            uint2 pkR, pkI;
            pkR.x = pk_bf16((accR[tile][0]+bR[0])*osc, (accR[tile][1]+bR[1])*osc);
            pkR.y = pk_bf16((accR[tile][2]+bR[2])*osc, (accR[tile][3]+bR[3])*osc);
            pkI.x = pk_bf16((accI[tile][0]+bI[0])*osc, (accI[tile][1]+bI[1])*osc);
            pkI.y = pk_bf16((accI[tile][2]+bI[2])*osc, (accI[tile][3]+bI[3])*osc);
            *(uint2*)&pr[idx] = pkR;
            *(uint2*)&pi[idx] = pkI;
        }
    } else if (z == 1) {
        // K fragment-order plane KF[h][c][frag][lane][8]
        unsigned short* kf = ws + 2*(size_t)PLANE_U;
        const int obase = o0 + wave*16 + g*4;       // d-range
        const int hh = obase >> 5, d0 = obase & 31;
        const int frag_re = (d0 >= 16) ? 1 : 0;
        const int bsel    = (d0 & 15) >> 3;
        const int e       = d0 & 7;                 // 0 or 4
        float bR[4], bI[4];
        #pragma unroll
        for (int r = 0; r < 4; ++r) { float2 bb = b2[obase + r]; bR[r] = bb.x; bI[r] = bb.y; }
        #pragma unroll
        for (int tile = 0; tile < 4; ++tile) {
            int s = s0 + tile*16 + lr;              // key
            int c = s >> 5;
            int i = s & 31;
            int r = (i & ~12) | ((i & 4) << 1) | ((i & 8) >> 1);  // kappa: swap bits 2,3
            int lane = bsel*32 + r;
            size_t base = ((size_t)(hh*64 + c)*4)*512 + lane*8 + e;
            uint2 pkR, pkI;
            pkR.x = pk_bf16(accR[tile][0]+bR[0], accR[tile][1]+bR[1]);
            pkR.y = pk_bf16(accR[tile][2]+bR[2], accR[tile][3]+bR[3]);
            pkI.x = pk_bf16(accI[tile][0]+bI[0], accI[tile][1]+bI[1]);
            pkI.y = pk_bf16(accI[tile][2]+bI[2], accI[tile][3]+bI[3]);
            *(uint2*)&kf[base + (size_t)frag_re*512]       = pkR;
            *(uint2*)&kf[base + (size_t)(2+frag_re)*512]   = pkI;
        }
    } else {
        // V fragment-order plane VF[h][c][frag][lane][8]
        unsigned short* vf = ws + 4*(size_t)PLANE_U;
        const int sbase = s0 + wave*16 + g*4;       // 4 consecutive keys
        const int c  = sbase >> 5;
        const int j0 = sbase & 31;
        const int frag_re = (j0 >= 16) ? 1 : 0;
        const int bsel    = (j0 & 15) >> 3;
        const int e       = j0 & 7;                 // 0 or 4
        #pragma unroll
        for (int tile = 0; tile < 4; ++tile) {
            int o = o0 + tile*16 + lr;
            int hh = o >> 5, d = o & 31;
            float2 bb = b2[o];
            int lane = bsel*32 + d;
            size_t base = ((size_t)(hh*64 + c)*4)*512 + lane*8 + e;
            uint2 pkR, pkI;
            pkR.x = pk_bf16(accR[tile][0]+bb.x, accR[tile][1]+bb.x);
            pkR.y = pk_bf16(accR[tile][2]+bb.x, accR[tile][3]+bb.x);
            pkI.x = pk_bf16(accI[tile][0]+bb.y, accI[tile][1]+bb.y);
            pkI.y = pk_bf16(accI[tile][2]+bb.y, accI[tile][3]+bb.y);
            *(uint2*)&vf[base + (size_t)frag_re*512]       = pkR;
            *(uint2*)&vf[base + (size_t)(2+frag_re)*512]   = pkI;
        }
    }
}

// ---------------- MFMA flash attention: 32x32x16, split-K 4 --------------
// K and V planes are stored in EXACT fragment-load order (KF/VF above), so
// every main-loop global load is one contiguous, fully-coalesced 1KB
// global_load_dwordx4 — no scatter, no transaction amplification. QK^T:
// S = mfma(K, Q) with the kappa permutation FOLDED INTO THE K PLANE, so
// P packs directly into the PV B-fragment (8 cvt_pk, no cross-lane, no
// LDS). PV: O^T = mfma(VF, P). Softmax: p = exp2(|s'|) with Q pre-scaled
// by log2(e)/sqrt(32). 4 waves/block x split-K 4; partials purely additive
// (no max tracking; |s| bounded). Combine: two-stage [2][32][33] float2.
#define RROW 33

__global__ __launch_bounds__(256, 4)
void attn_mfma(const unsigned short* __restrict__ ws, float* __restrict__ out)
{
    const int bid   = blockIdx.x;       // 64 q-blocks x 16 heads
    const int h     = bid & (NH - 1);   // bid%8 = head%8 -> per-XCD KV locality
    const int qblk  = bid >> 4;         // 0..63
    const int wave  = threadIdx.x >> 6; // 0..3 -> k-range owner
    const int l     = threadIdx.x & 63;
    const int q     = l & 31;           // q-col of QK D; q-row of output
    const int b     = l >> 5;

    const unsigned short* qr = ws + 0*(size_t)PLANE_U + (size_t)h*S_LEN*HD;
    const unsigned short* qi = ws + 1*(size_t)PLANE_U + (size_t)h*S_LEN*HD;
    const unsigned short* kf = ws + 2*(size_t)PLANE_U + ((size_t)h << 17);  // 64c*4*512
    const unsigned short* vf = ws + 4*(size_t)PLANE_U + ((size_t)h << 17);

    const int q0 = qblk * 32;

    // Q fragments (B-operand): lane supplies Q[q][d = b*8+j] (lo) / +16 (hi)
    bf16x8 bQr_lo = *(const bf16x8*)&qr[(size_t)(q0 + q)*HD + b*8];
    bf16x8 bQr_hi = *(const bf16x8*)&qr[(size_t)(q0 + q)*HD + 16 + b*8];
    bf16x8 bQi_lo = *(const bf16x8*)&qi[(size_t)(q0 + q)*HD + b*8];
    bf16x8 bQi_hi = *(const bf16x8*)&qi[(size_t)(q0 + q)*HD + 16 + b*8];

    // LDS only for the end-of-kernel two-stage combine: [2][32][33] float2
    __shared__ __align__(16) float2 red[2*32*RROW];

    f32x16 accR, accI;
    #pragma unroll
    for (int r = 0; r < 16; ++r) { accR[r] = 0.f; accI[r] = 0.f; }
    float lsum = 0.f;

    const f32x16 z16 = {0,0,0,0,0,0,0,0,0,0,0,0,0,0,0,0};
    const int kbeg = wave * 512;
    for (int k0 = kbeg; k0 < kbeg + 512; k0 += 32) {
        const size_t fb = (size_t)(k0 >> 5) * 2048 + l*8;

        // ---- V fragments (contiguous 1KB loads; slack = QK chain) ----
        bf16x8 aVr_lo = *(const bf16x8*)&vf[fb];
        bf16x8 aVr_hi = *(const bf16x8*)&vf[fb + 512];
        bf16x8 aVi_lo = *(const bf16x8*)&vf[fb + 1024];
        bf16x8 aVi_hi = *(const bf16x8*)&vf[fb + 1536];

        // ---- K fragments (contiguous 1KB loads, kappa pre-folded) ----
        bf16x8 aKr_lo = *(const bf16x8*)&kf[fb];
        bf16x8 aKr_hi = *(const bf16x8*)&kf[fb + 512];
        bf16x8 aKi_lo = *(const bf16x8*)&kf[fb + 1024];
        bf16x8 aKi_hi = *(const bf16x8*)&kf[fb + 1536];
        bf16x8 aKin_lo, aKin_hi;    // -Ki (transient)
        #pragma unroll
        for (int j = 0; j < 4; ++j) {
            ((unsigned int*)&aKin_lo)[j] = ((const unsigned int*)&aKi_lo)[j] ^ 0x80008000u;
            ((unsigned int*)&aKin_hi)[j] = ((const unsigned int*)&aKi_hi)[j] ^ 0x80008000u;
        }
        // ---- QK^T: 8 mfma, two independent 4-chains ----
        f32x16 sR = __builtin_amdgcn_mfma_f32_32x32x16_bf16(aKr_lo,  bQr_lo, z16, 0, 0, 0);
        f32x16 sI = __builtin_amdgcn_mfma_f32_32x32x16_bf16(aKin_lo, bQr_lo, z16, 0, 0, 0);
        sR = __builtin_amdgcn_mfma_f32_32x32x16_bf16(aKr_hi,  bQr_hi, sR, 0, 0, 0);
        sI = __builtin_amdgcn_mfma_f32_32x32x16_bf16(aKin_hi, bQr_hi, sI, 0, 0, 0);
        sR = __builtin_amdgcn_mfma_f32_32x32x16_bf16(aKi_lo,  bQi_lo, sR, 0, 0, 0);
        sI = __builtin_amdgcn_mfma_f32_32x32x16_bf16(aKr_lo,  bQi_lo, sI, 0, 0, 0);
        sR = __builtin_amdgcn_mfma_f32_32x32x16_bf16(aKi_hi,  bQi_hi, sR, 0, 0, 0);
        sI = __builtin_amdgcn_mfma_f32_32x32x16_bf16(aKr_hi,  bQi_hi, sI, 0, 0, 0);
        // ---- softmax: p[r] lands exactly in PV B-frag order ----
        bf16x8 bP1, bP2;
        unsigned int* p1 = (unsigned int*)&bP1;
        unsigned int* p2 = (unsigned int*)&bP2;
        #pragma unroll
        for (int r2 = 0; r2 < 8; ++r2) {
            int r = 2*r2;
            float v0 = EXP2(__builtin_amdgcn_sqrtf(fmaf(sR[r],   sR[r],   sI[r]*sI[r])));
            float v1 = EXP2(__builtin_amdgcn_sqrtf(fmaf(sR[r+1], sR[r+1], sI[r+1]*sI[r+1])));
            lsum += v0 + v1;
            if (r2 < 4) p1[r2]     = pk_bf16(v0, v1);
            else        p2[r2 - 4] = pk_bf16(v0, v1);
        }
        // ---- PV: A = VF (contiguous), B = P in-register ----
        accR = __builtin_amdgcn_mfma_f32_32x32x16_bf16(aVr_lo, bP1, accR, 0, 0, 0);
        accI = __builtin_amdgcn_mfma_f32_32x32x16_bf16(aVi_lo, bP1, accI, 0, 0, 0);
        accR = __builtin_amdgcn_mfma_f32_32x32x16_bf16(aVr_hi, bP2, accR, 0, 0, 0);
        accI = __builtin_amdgcn_mfma_f32_32x32x16_bf16(aVi_hi, bP2, accI, 0, 0, 0);
    }

    // lane pair (l, l^32) handled complementary key halves of the same q
    lsum += __shfl_xor(lsum, 32);

    // ---- two-stage combine: waves 0,1 write; 2,3 add; all reduce ----
    const int rrow = ((wave & 1) * 32 + q) * RROW;
    __syncthreads();
    if (wave < 2) {
        #pragma unroll
        for (int r = 0; r < 16; ++r) {
            int d = (r & 3) + 8*(r >> 2) + 4*b;   // PV D row = output d
            red[rrow + d] = make_float2(accR[r], accI[r]);
        }
        if (b == 0) red[rrow + 32].x = lsum;
    }
    __syncthreads();
    if (wave >= 2) {
        #pragma unroll
        for (int r = 0; r < 16; ++r) {
            int d = (r & 3) + 8*(r >> 2) + 4*b;
            float2 v = red[rrow + d];
            v.x += accR[r]; v.y += accI[r];
            red[rrow + d] = v;
        }
        if (b == 0) red[rrow + 32].x += lsum;
    }
    __syncthreads();

    // thread i: q-row = i>>3, d = (i&7)*4 .. +3 ; sum 2 stage-partials
    {
        const int i  = threadIdx.x;
        const int oq = i >> 3;
        const int d0 = (i & 7) * 4;
        float sl = red[oq*RROW + 32].x + red[(32 + oq)*RROW + 32].x;
        float inv = 1.0f / sl;
        float2* o2 = (float2*)out;
        #pragma unroll
        for (int dd = 0; dd < 4; ++dd) {
            int d = d0 + dd;
            float2 v0 = red[oq*RROW + d];
            float2 v1 = red[(32 + oq)*RROW + d];
            o2[(size_t)(q0 + oq)*C_DIM + h*HD + d] =
                make_float2((v0.x + v1.x)*inv, (v0.y + v1.y)*inv);
        }
    }
}

extern "C" void kernel_launch(void* const* d_in, const int* in_sizes, int n_in,
                              void* d_out, int out_size, void* d_ws, size_t ws_size,
                              hipStream_t stream)
{
    const float* Q  = (const float*)d_in[0];
    const float* V  = (const float*)d_in[1];
    const float* K  = (const float*)d_in[2];
    const float* Wq = (const float*)d_in[3];
    const float* bq = (const float*)d_in[4];
    const float* Wk = (const float*)d_in[5];
    const float* bk = (const float*)d_in[6];
    const float* Wv = (const float*)d_in[7];
    const float* bv = (const float*)d_in[8];
    unsigned short* ws = (unsigned short*)d_ws;   // q,qi planes + KF (4MB) + VF (4MB) = 12MB
    float* out = (float*)d_out;

    dim3 gp(S_LEN/64, C_DIM/64, 3);
    proj_mfma<<<gp, 256, 0, stream>>>(Q, V, K, Wq, bq, Wk, bk, Wv, bv, ws);

    attn_mfma<<<dim3(64*NH), 256, 0, stream>>>(ws, out);
}